// Round 8
// baseline (1143.950 us; speedup 1.0000x reference)
//
#include <hip/hip_runtime.h>
#include <math.h>

#define BB 128
#define TT 1024
#define DD 128
#define HH 64
#define G3 192   // 3*H
#define KK 32
#define CH 32

// ---------------------------------------------------------------------------
// R8 restructure. R7 falsified the scheduling theory (64 free CUs, same 877);
// the 732us consumer loop itself is the target. Its step (1712 cyc) is ~3x
// its arithmetic because gates live in 3 waves -> gbuf LDS roundtrip + 5-wave
// barrier EVERY step, with viterbi's serial chain in the same barrier race.
// New design:
//   K1 xproj: verbatim R0 kernel (166us, proven).
//   K2 gruvit: grid 256 x 256thr.
//     blocks 0..127 (GRU, wave0 only, ZERO barriers): lane j holds z-gate
//       weights + Dk col j in regs (128 pinned, R3-proven size class); r/h
//       gate weights in LDS, lane-private layout (lane j wrote col j -> no
//       sync). Per step: one 16x-unrolled loop does 64 readlanes x 4 FMAs
//       (z, r, hgate, pot-at-lag-1: step t broadcasts h(t-1), so pot(t-1)
//       accumulates free, exact R0 p0..p3 order). Per-step pot store to
//       out_pot (no barriers -> no drain points); per-chunk fence+flag.
//     blocks 128..255 (VIT): stager wave spins on pot-chunk flags (proven
//       R6/R7 pattern), stages 4KB chunks to LDS double-buffer; vit wave
//       runs R0's transition verbatim, barrier-free within a chunk (33
//       barriers total, not 1026); then R0 backtrack A/B/C.
// GRU math bitwise-identical to R0 (same per-gate 4-acc k-ascending order,
// same sigmoid/tanh forms, same pot order, same viterbi tie-breaks).
// ---------------------------------------------------------------------------
#define BCAST(v, l) __int_as_float(__builtin_amdgcn_readlane(__float_as_int(v), (l)))

__device__ int g_pflags[BB * 32];   // zero-initialized at module load

// ============================ K1: xproj (R0 verbatim) =======================
__global__ __launch_bounds__(256, 2) void xproj_kernel(const float* __restrict__ X,
                                                       const float* __restrict__ Wk,
                                                       const float* __restrict__ gbias,
                                                       float* __restrict__ xp) {
    __shared__ float Xs[64 * 132];
    __shared__ float Ws[128 * 68];
    const int tid = threadIdx.x;
    const int row0 = blockIdx.x * 64;
    const int cg = blockIdx.y;
#pragma unroll
    for (int it = 0; it < 8; ++it) {
        int idx = it * 1024 + tid * 4;
        int r = idx >> 7, c = idx & 127;
        float4 v = *(const float4*)&X[((size_t)(row0 + r)) * DD + c];
        *(float4*)&Xs[r * 132 + c] = v;
    }
#pragma unroll
    for (int it = 0; it < 8; ++it) {
        int idx = it * 1024 + tid * 4;
        int k = idx >> 6, c = idx & 63;
        float4 v = *(const float4*)&Wk[(size_t)k * G3 + cg * 64 + c];
        *(float4*)&Ws[k * 68 + c] = v;
    }
    __syncthreads();
    const int tr = tid >> 4, tc = tid & 15;
    const int r0 = tr * 4, c0 = tc * 4;
    float acc[4][4];
#pragma unroll
    for (int r = 0; r < 4; ++r)
#pragma unroll
        for (int c = 0; c < 4; ++c) acc[r][c] = 0.f;
#pragma unroll 4
    for (int k = 0; k < DD; k += 4) {
        float a[4][4];
#pragma unroll
        for (int r = 0; r < 4; ++r) {
            float4 t = *(const float4*)&Xs[(r0 + r) * 132 + k];
            a[r][0] = t.x; a[r][1] = t.y; a[r][2] = t.z; a[r][3] = t.w;
        }
#pragma unroll
        for (int kk = 0; kk < 4; ++kk) {
            float4 b = *(const float4*)&Ws[(k + kk) * 68 + c0];
#pragma unroll
            for (int r = 0; r < 4; ++r) {
                acc[r][0] += a[r][kk] * b.x;
                acc[r][1] += a[r][kk] * b.y;
                acc[r][2] += a[r][kk] * b.z;
                acc[r][3] += a[r][kk] * b.w;
            }
        }
    }
    float4 bias = *(const float4*)&gbias[cg * 64 + c0];
#pragma unroll
    for (int r = 0; r < 4; ++r) {
        float4 o;
        o.x = acc[r][0] + bias.x; o.y = acc[r][1] + bias.y;
        o.z = acc[r][2] + bias.z; o.w = acc[r][3] + bias.w;
        *(float4*)&xp[((size_t)(row0 + r0 + r)) * G3 + cg * 64 + c0] = o;
    }
}

// ============================ K2: GRU + pot | viterbi =======================
__global__ __launch_bounds__(256, 1)
void gruvit_kernel(const float* __restrict__ xp,
                   const float* __restrict__ Wr,
                   const float* __restrict__ gbias,
                   const int* __restrict__ mask,
                   const float* __restrict__ Dk,
                   const float* __restrict__ db,
                   const float* __restrict__ chain,
                   const float* __restrict__ lb,
                   const float* __restrict__ rb,
                   float* __restrict__ out_pot,
                   float* __restrict__ out_dec,
                   float* __restrict__ out_slen,
                   float* __restrict__ out_chn) {
    const int tid = threadIdx.x;
    const int w = tid >> 6;
    const int l = tid & 63;

    __shared__ __align__(16) float wl[2][16][64][4];               // 32768 B (GRU)
    __shared__ unsigned char bp[(TT - 1) * KK];                    // 32736 B (vit)
    __shared__ __align__(16) unsigned char table[32 * 32 * KK];    // 32768 B (vit)
    __shared__ __align__(16) float potbuf[2][CH][KK];              // 8192 B (vit)
    __shared__ int ent[32];
    __shared__ int last_tag_s;

    if (blockIdx.x < BB) {
        // =================== GRU block: single wave, zero barriers ==========
        if (w != 0) return;
        const int b = blockIdx.x;
        const int bTT = b * TT;
        const int j = l;
        const int k = l & 31;
        // r/h-gate weights -> LDS, lane-private columns (no sync needed)
        for (int g = 0; g < 2; ++g)
            for (int c4 = 0; c4 < 16; ++c4)
                for (int e = 0; e < 4; ++e)
                    wl[g][c4][j][e] = Wr[(size_t)(4 * c4 + e) * G3 + 64 + g * 64 + j];
        // z-gate weights + Dk column in regs (128 pinned, proven size class)
        float wgz[64];
#pragma unroll
        for (int c = 0; c < 64; ++c) wgz[c] = Wr[(size_t)c * G3 + j];
#pragma unroll
        for (int c = 0; c < 64; ++c) asm volatile("" : "+v"(wgz[c]));
        float dk[64];
#pragma unroll
        for (int c = 0; c < 64; ++c) dk[c] = Dk[c * KK + k];
#pragma unroll
        for (int c = 0; c < 64; ++c) asm volatile("" : "+v"(dk[c]));
        const float bwz = gbias[G3 + j], bwr = gbias[G3 + 64 + j], bwh = gbias[G3 + 128 + j];
        const float dbk = db[k], lbk = lb[k], rbk = rb[k];
        // sequence length (R0 code)
        int sl = 0;
#pragma unroll
        for (int q = 0; q < 16; ++q) sl += mask[bTT + q * 64 + l];
#pragma unroll
        for (int d = 32; d >= 1; d >>= 1) sl += __shfl_xor(sl, d, 64);
        if (l == 0) out_slen[b] = (float)sl;
        const float* xpg = xp + (size_t)bTT * G3;
        float* potg = out_pot + (size_t)bTT * KK;
        float h = 0.f;
        float xz = xpg[j], xr = xpg[64 + j], xh = xpg[128 + j];
        int m0 = mask[bTT];
        for (int t = 0; t < TT; ++t) {
            // prefetch t+1 (hidden under this step's ~800cyc of compute)
            float nxz = 0.f, nxr = 0.f, nxh = 0.f; int nm = 0;
            if (t + 1 < TT) {
                const float* p1 = xpg + (size_t)(t + 1) * G3;
                nxz = p1[j]; nxr = p1[64 + j]; nxh = p1[128 + j];
                nm = mask[bTT + t + 1];
            }
            // fused gate loop: broadcasts h(t-1); z,r,hgate + pot(t-1) lag-1
            float az0 = bwz, az1 = 0.f, az2 = 0.f, az3 = 0.f;
            float ar0 = bwr, ar1 = 0.f, ar2 = 0.f, ar3 = 0.f;
            float ah0 = bwh, ah1 = 0.f, ah2 = 0.f, ah3 = 0.f;
            float p0 = dbk, p1a = 0.f, p2a = 0.f, p3a = 0.f;
#pragma unroll
            for (int c4 = 0; c4 < 16; ++c4) {
                float4 wr4 = *(const float4*)&wl[0][c4][j][0];
                float4 wh4 = *(const float4*)&wl[1][c4][j][0];
                float h0 = BCAST(h, 4 * c4 + 0), h1 = BCAST(h, 4 * c4 + 1);
                float h2 = BCAST(h, 4 * c4 + 2), h3 = BCAST(h, 4 * c4 + 3);
                az0 += h0 * wgz[4 * c4 + 0]; az1 += h1 * wgz[4 * c4 + 1];
                az2 += h2 * wgz[4 * c4 + 2]; az3 += h3 * wgz[4 * c4 + 3];
                ar0 += h0 * wr4.x; ar1 += h1 * wr4.y; ar2 += h2 * wr4.z; ar3 += h3 * wr4.w;
                ah0 += h0 * wh4.x; ah1 += h1 * wh4.y; ah2 += h2 * wh4.z; ah3 += h3 * wh4.w;
                p0 += h0 * dk[4 * c4 + 0]; p1a += h1 * dk[4 * c4 + 1];
                p2a += h2 * dk[4 * c4 + 2]; p3a += h3 * dk[4 * c4 + 3];
            }
            // pot(t-1) finalize + store (exact R0 order); skip at t==0
            if (t > 0) {
                const int tp = t - 1;
                float pot = (p0 + p1a) + (p2a + p3a);
                if (tp == 0) pot += lbk;
                if (tp == sl - 1) pot += rbk;
                if (l < 32) potg[(size_t)tp * KK + k] = pot;
                if ((t & 31) == 0) {                      // chunk (t-1)>>5 done
                    if (l == 0) {
                        __threadfence();
                        atomicExch(&g_pflags[b * 32 + ((t - 1) >> 5)], 1);
                    }
                }
            }
            // h update (bitwise-identical to R0)
            float az = (az0 + az1) + (az2 + az3);
            float ar = (ar0 + ar1) + (ar2 + ar3);
            float ah = (ah0 + ah1) + (ah2 + ah3);
            float z = 1.f / (1.f + __expf(-(xz + az)));
            float r = 1.f / (1.f + __expf(-(xr + ar)));
            float y = xh + r * ah;
            float hh = 1.f - 2.f / (1.f + __expf(2.f * y));
            float hn = z * h + (1.f - z) * hh;
            h = (m0 != 0) ? hn : h;
            xz = nxz; xr = nxr; xh = nxh; m0 = nm;
        }
        // epilogue: pot(TT-1) from final h
        {
            float p0 = dbk, p1a = 0.f, p2a = 0.f, p3a = 0.f;
#pragma unroll
            for (int c4 = 0; c4 < 16; ++c4) {
                p0  += BCAST(h, 4 * c4 + 0) * dk[4 * c4 + 0];
                p1a += BCAST(h, 4 * c4 + 1) * dk[4 * c4 + 1];
                p2a += BCAST(h, 4 * c4 + 2) * dk[4 * c4 + 2];
                p3a += BCAST(h, 4 * c4 + 3) * dk[4 * c4 + 3];
            }
            float pot = (p0 + p1a) + (p2a + p3a);
            if (TT - 1 == sl - 1) pot += rbk;
            if (l < 32) potg[(size_t)(TT - 1) * KK + k] = pot;
            if (l == 0) {
                __threadfence();
                atomicExch(&g_pflags[b * 32 + 31], 1);
            }
        }
        return;
    }

    // =================== VIT block: stager + viterbi + backtrack ============
    const int b = blockIdx.x - BB;
    const int bTT = b * TT;
    const float* potg = out_pot + (size_t)bTT * KK;
    const int k = l & 31;
    const int hf = l >> 5;
    const int addrx = (l ^ 32) * 4;
    float ccol[16];
    int addr[16];
    if (w == 1) {
#pragma unroll
        for (int m = 0; m < 16; ++m) {
            ccol[m] = chain[(hf * 16 + m) * KK + k];
            addr[m] = (hf * 16 + m) * 4;
        }
#pragma unroll
        for (int m = 0; m < 16; ++m) asm volatile("" : "+v"(ccol[m]));
    }
    // stage chunk 0
    if (w == 0) {
        if (l == 0) {
            while (atomicAdd(&g_pflags[b * 32 + 0], 0) == 0) __builtin_amdgcn_s_sleep(8);
        }
        __threadfence();                                  // acquire
#pragma unroll
        for (int q = 0; q < 4; ++q) {
            float4 v = *(const float4*)&potg[(size_t)(q * 64 + l) * 4];
            ((float4*)&potbuf[0][0][0])[q * 64 + l] = v;
        }
    }
    __syncthreads();                                      // B0: chunk 0 ready
    float s = 0.f;
    for (int c = 0; c < 32; ++c) {
        if (w == 0 && c + 1 < 32) {                       // stage chunk c+1
            if (l == 0) {
                while (atomicAdd(&g_pflags[b * 32 + c + 1], 0) == 0)
                    __builtin_amdgcn_s_sleep(8);
            }
            __threadfence();
            const float* src = potg + (size_t)(c + 1) * CH * KK;
#pragma unroll
            for (int q = 0; q < 4; ++q) {
                float4 v = *(const float4*)&src[(size_t)(q * 64 + l) * 4];
                ((float4*)&potbuf[(c + 1) & 1][0][0])[q * 64 + l] = v;
            }
        }
        if (w == 1) {                                     // viterbi chunk c
            for (int ll = 0; ll < 32; ++ll) {
                const int t = c * 32 + ll;
                float pot = potbuf[c & 1][ll][k];
                if (t == 0) {
                    s = pot;
                } else {
                    const int si = __float_as_int(s);
                    float cc[16];
#pragma unroll
                    for (int m = 0; m < 16; ++m)
                        cc[m] = __int_as_float(__builtin_amdgcn_ds_bpermute(addr[m], si)) + ccol[m];
                    float v1[8]; int i1[8];
#pragma unroll
                    for (int p = 0; p < 8; ++p) {
                        bool tk = cc[2 * p + 1] > cc[2 * p];
                        v1[p] = tk ? cc[2 * p + 1] : cc[2 * p];
                        i1[p] = hf * 16 + (tk ? 2 * p + 1 : 2 * p);
                    }
                    float v2[4]; int i2[4];
#pragma unroll
                    for (int p = 0; p < 4; ++p) {
                        bool tk = v1[2 * p + 1] > v1[2 * p];
                        v2[p] = tk ? v1[2 * p + 1] : v1[2 * p];
                        i2[p] = tk ? i1[2 * p + 1] : i1[2 * p];
                    }
                    float v3[2]; int i3[2];
#pragma unroll
                    for (int p = 0; p < 2; ++p) {
                        bool tk = v2[2 * p + 1] > v2[2 * p];
                        v3[p] = tk ? v2[2 * p + 1] : v2[2 * p];
                        i3[p] = tk ? i2[2 * p + 1] : i2[2 * p];
                    }
                    bool tk = v3[1] > v3[0];
                    float bv = tk ? v3[1] : v3[0];
                    int bi = tk ? i3[1] : i3[0];
                    float ov = __int_as_float(__builtin_amdgcn_ds_bpermute(addrx, __float_as_int(bv)));
                    int   oi = __builtin_amdgcn_ds_bpermute(addrx, bi);
                    bool take = (ov > bv) || (ov == bv && oi < bi);
                    if (take) { bv = ov; bi = oi; }
                    if (l < 32) bp[(t - 1) * KK + k] = (unsigned char)bi;
                    s = bv + pot;
                }
            }
        }
        __syncthreads();                                  // chunk boundary
    }
    if (w == 1) {                                         // last tag
        float bv = s; int bi = k;
#pragma unroll
        for (int d = 16; d >= 1; d >>= 1) {
            float ov = __shfl_xor(bv, d, 64);
            int   oi = __shfl_xor(bi, d, 64);
            bool take = (ov > bv) || (ov == bv && oi < bi);
            if (take) { bv = ov; bi = oi; }
        }
        if (l == 0) last_tag_s = bi;
    }
    __syncthreads();
    // ---- Phase A: chunk-parallel backtrack (8 groups over 32 chunks) ----
    {
        const int kk2 = tid & 31;
        const int grp = tid >> 5;                         // 0..7
        for (int c = grp; c < 32; c += 8) {
            int tag = kk2;
            for (int ll = 31; ll >= 0; --ll) {
                const int t = c * 32 + ll;
                if (t < TT - 1) tag = bp[t * KK + tag];
                table[(c * 32 + ll) * KK + kk2] = (unsigned char)tag;
            }
        }
    }
    __syncthreads();
    if (tid == 0) {                                       // Phase B: stitch
        int e = last_tag_s;
        ent[31] = e;
        for (int c = 30; c >= 0; --c) { e = table[(c + 1) * 32 * KK + e]; ent[c] = e; }
    }
    __syncthreads();
    for (int t = tid; t < TT; t += 256) {                 // Phase C: emit
        const int c = t >> 5, ll = t & 31;
        out_dec[(size_t)bTT + t] = (float)table[(c * 32 + ll) * KK + ent[c]];
    }
    if (blockIdx.x == BB) {
        for (int i2 = tid; i2 < KK * KK; i2 += 256) out_chn[i2] = chain[i2];
    }
    // re-zero this batch's flags for the next launch/replay
    for (int i2 = tid; i2 < 32; i2 += 256) atomicExch(&g_pflags[b * 32 + i2], 0);
}

// ---------------------------------------------------------------------------
extern "C" void kernel_launch(void* const* d_in, const int* in_sizes, int n_in,
                              void* d_out, int out_size, void* d_ws, size_t ws_size,
                              hipStream_t stream) {
    const float* X     = (const float*)d_in[0];
    const int*   mask  = (const int*)d_in[1];
    const float* Wk    = (const float*)d_in[2];   // [128,192]
    const float* Wr    = (const float*)d_in[3];   // [64,192]
    const float* gb    = (const float*)d_in[4];   // [2,192]
    const float* Dk    = (const float*)d_in[5];   // [64,32]
    const float* db    = (const float*)d_in[6];   // [32]
    const float* chain = (const float*)d_in[7];   // [32,32]
    const float* lb    = (const float*)d_in[8];
    const float* rb    = (const float*)d_in[9];

    float* out = (float*)d_out;
    float* out_dec  = out;                                   // [B,T]
    float* out_pot  = out + (size_t)BB * TT;                 // [B,T,K]
    float* out_slen = out + (size_t)BB * TT + (size_t)BB * TT * KK;        // [B]
    float* out_chn  = out_slen + BB;                         // [K,K]

    float* xp = (float*)d_ws;                                // [B*T,192]

    xproj_kernel<<<dim3((BB * TT) / 64, 3), dim3(256), 0, stream>>>(X, Wk, gb, xp);
    gruvit_kernel<<<dim3(2 * BB), dim3(256), 0, stream>>>(xp, Wr, gb, mask, Dk, db,
                                                          chain, lb, rb, out_pot,
                                                          out_dec, out_slen, out_chn);
}

// Round 9
// 745.858 us; speedup vs baseline: 1.5337x; 1.5337x over previous
//
#include <hip/hip_runtime.h>
#include <math.h>

#define BB 128
#define TT 1024
#define DD 128
#define HH 64
#define G3 192   // 3*H
#define KK 32
#define CH 32

// ---------------------------------------------------------------------------
// R9: isolate the viterbi-straggler hypothesis.
// R8 post-mortem: single-wave GRU = 256 FMA-insts/step on ONE wave (512cyc
// issue) + 8-way-conflicted ds_read_b128 -> 2300cyc step. R0's 3-wave gate
// split was right. R8's VIT block (flag-spin stager + chunked vit + backtrack)
// PASSED across ~70 replays -> proven, reused verbatim.
// Design:
//   K1 xproj: R0 verbatim (166us proven).
//   K2 grid 256 x 256thr:
//     blocks 0..127  GRU: R0's waves 0-3 BYTE-FOR-BYTE (gates in 3 waves,
//       pot+staging wave, 1 barrier/step) minus the viterbi wave. Publishes
//       pot chunk cf flag at (i&31)==4 of the following chunk (flush stores
//       long complete -> fence drains nothing); chunks 30,31 post-loop.
//     blocks 128..255 VIT: R8's block verbatim (consumes out_pot chunks).
// In R0, wave4(vit, prio0) shared SIMD0 with wave0(prio1): its ~400cyc serial
// bpermute chain started ~320cyc late and every one of 1026 barriers waited
// for it. Removing it from the barrier race is the single variable tested.
// ---------------------------------------------------------------------------
#define BCAST(v, l) __int_as_float(__builtin_amdgcn_readlane(__float_as_int(v), (l)))

__device__ int g_pflags[BB * 32];   // zero-initialized at module load

// ============================ K1: xproj (R0 verbatim) =======================
__global__ __launch_bounds__(256, 2) void xproj_kernel(const float* __restrict__ X,
                                                       const float* __restrict__ Wk,
                                                       const float* __restrict__ gbias,
                                                       float* __restrict__ xp) {
    __shared__ float Xs[64 * 132];
    __shared__ float Ws[128 * 68];
    const int tid = threadIdx.x;
    const int row0 = blockIdx.x * 64;
    const int cg = blockIdx.y;
#pragma unroll
    for (int it = 0; it < 8; ++it) {
        int idx = it * 1024 + tid * 4;
        int r = idx >> 7, c = idx & 127;
        float4 v = *(const float4*)&X[((size_t)(row0 + r)) * DD + c];
        *(float4*)&Xs[r * 132 + c] = v;
    }
#pragma unroll
    for (int it = 0; it < 8; ++it) {
        int idx = it * 1024 + tid * 4;
        int k = idx >> 6, c = idx & 63;
        float4 v = *(const float4*)&Wk[(size_t)k * G3 + cg * 64 + c];
        *(float4*)&Ws[k * 68 + c] = v;
    }
    __syncthreads();
    const int tr = tid >> 4, tc = tid & 15;
    const int r0 = tr * 4, c0 = tc * 4;
    float acc[4][4];
#pragma unroll
    for (int r = 0; r < 4; ++r)
#pragma unroll
        for (int c = 0; c < 4; ++c) acc[r][c] = 0.f;
#pragma unroll 4
    for (int k = 0; k < DD; k += 4) {
        float a[4][4];
#pragma unroll
        for (int r = 0; r < 4; ++r) {
            float4 t = *(const float4*)&Xs[(r0 + r) * 132 + k];
            a[r][0] = t.x; a[r][1] = t.y; a[r][2] = t.z; a[r][3] = t.w;
        }
#pragma unroll
        for (int kk = 0; kk < 4; ++kk) {
            float4 b = *(const float4*)&Ws[(k + kk) * 68 + c0];
#pragma unroll
            for (int r = 0; r < 4; ++r) {
                acc[r][0] += a[r][kk] * b.x;
                acc[r][1] += a[r][kk] * b.y;
                acc[r][2] += a[r][kk] * b.z;
                acc[r][3] += a[r][kk] * b.w;
            }
        }
    }
    float4 bias = *(const float4*)&gbias[cg * 64 + c0];
#pragma unroll
    for (int r = 0; r < 4; ++r) {
        float4 o;
        o.x = acc[r][0] + bias.x; o.y = acc[r][1] + bias.y;
        o.z = acc[r][2] + bias.z; o.w = acc[r][3] + bias.w;
        *(float4*)&xp[((size_t)(row0 + r0 + r)) * G3 + cg * 64 + c0] = o;
    }
}

// ================== K2: GRU blocks (R0 waves 0-3) | VIT blocks (R8) =========
__global__ __launch_bounds__(256, 1)
void gruvit_kernel(const float* __restrict__ xp,
                   const float* __restrict__ Wr,
                   const float* __restrict__ gbias,
                   const int* __restrict__ mask,
                   const float* __restrict__ Dk,
                   const float* __restrict__ db,
                   const float* __restrict__ chain,
                   const float* __restrict__ lb,
                   const float* __restrict__ rb,
                   float* __restrict__ out_pot,
                   float* __restrict__ out_dec,
                   float* __restrict__ out_slen,
                   float* __restrict__ out_chn) {
    __shared__ __align__(16) unsigned char smem[73856];
    const int tid = threadIdx.x;
    const int w = tid >> 6;
    const int l = tid & 63;

    if (blockIdx.x < BB) {
        // =================== GRU block: R0 waves 0-3 verbatim ===============
        const int b = blockIdx.x;
        const int bTT = b * TT;
        float (*gbuf)[4 * HH]     = (float (*)[4 * HH])(smem);           // 2048
        float (*hbuf)[HH]         = (float (*)[HH])(smem + 2048);        // 1024
        float (*potring)[KK]      = (float (*)[KK])(smem + 3072);        // 8192
        float (*xpstage)[CH * G3] = (float (*)[CH * G3])(smem + 11264);  // 49152
        int (*maskst)[CH]         = (int (*)[CH])(smem + 60416);         // 256

        if (w < 3) {
            // ---- GRU gate waves (R0 verbatim) ----
            const int j = l;
            float wg[HH];
#pragma unroll
            for (int i2 = 0; i2 < HH; ++i2) wg[i2] = Wr[i2 * G3 + w * HH + j];
#pragma unroll
            for (int i2 = 0; i2 < HH; ++i2) asm volatile("" : "+v"(wg[i2]));
            const float bw = gbias[G3 + w * HH + j];
            __builtin_amdgcn_s_setprio(1);
            float h = 0.f;
            __syncthreads();                                  // pre-loop barrier
            float xv0 = xpstage[0][tid];                      // xv(0)
            int m0 = maskst[0][0];                            // m(0), broadcast
            for (int i = 0; i < TT + 2; ++i) {
                if (i < TT) {
                    float a0 = bw, a1 = 0.f, a2 = 0.f, a3 = 0.f;
#pragma unroll
                    for (int c = 0; c < HH; c += 4) {
                        a0 += BCAST(h, c + 0) * wg[c + 0];
                        a1 += BCAST(h, c + 1) * wg[c + 1];
                        a2 += BCAST(h, c + 2) * wg[c + 2];
                        a3 += BCAST(h, c + 3) * wg[c + 3];
                    }
                    float a = (a0 + a1) + (a2 + a3);
                    float g = (w == 2) ? a : 1.f / (1.f + __expf(-(xv0 + a)));
                    gbuf[i & 1][w * HH + j] = g;
                    if (w == 2) gbuf[i & 1][3 * HH + j] = xv0;
                }
                __syncthreads();
                if (i < TT) {
                    float z  = gbuf[i & 1][j];
                    float r  = gbuf[i & 1][HH + j];
                    float rh = gbuf[i & 1][2 * HH + j];
                    float xh = gbuf[i & 1][3 * HH + j];
                    float y = xh + r * rh;
                    float hh = 1.f - 2.f / (1.f + __expf(2.f * y));   // tanh
                    float hn = z * h + (1.f - z) * hh;
                    hn = (m0 != 0) ? hn : h;
                    h = hn;
                    if (w == 0) hbuf[i & 3][j] = hn;
                    if (i < TT - 1) {                        // prefetch step i+1
                        const int t1 = i + 1;
                        xv0 = xpstage[(t1 >> 5) & 1][(t1 & 31) * G3 + tid];
                        m0  = maskst[(t1 >> 5) & 1][t1 & 31];
                    }
                }
            }
        } else {
            // ---- pot matvec + chunk staging wave (R0 verbatim + flags) ----
            const int k = l & 31;
            int sl = 0;
#pragma unroll
            for (int q = 0; q < 16; ++q) sl += mask[bTT + q * 64 + l];
#pragma unroll
            for (int d = 32; d >= 1; d >>= 1) sl += __shfl_xor(sl, d, 64);
            if (l == 0) out_slen[b] = (float)sl;
            float dk[HH];
#pragma unroll
            for (int i2 = 0; i2 < HH; ++i2) dk[i2] = Dk[i2 * KK + k];
#pragma unroll
            for (int i2 = 0; i2 < HH; ++i2) asm volatile("" : "+v"(dk[i2]));
            const float dbk = db[k], lbk = lb[k], rbk = rb[k];
            const float* xpg = xp + (size_t)bTT * G3;
            float* potg = out_pot + (size_t)bTT * KK;
            // stage chunk 0
#pragma unroll
            for (int q = 0; q < 24; ++q) {
                float4 v = *(const float4*)&xpg[q * 256 + l * 4];
                *(float4*)&xpstage[0][q * 256 + l * 4] = v;
            }
            if (l < CH) maskst[0][l] = mask[bTT + l];
            __syncthreads();                                  // pre-loop barrier
            for (int i = 0; i < TT + 2; ++i) {
                if ((i & 31) == 0) {
                    const int cn = (i >> 5) + 1;              // stage chunk cn
                    if (cn < 32) {
                        const float* src = xpg + (size_t)cn * CH * G3;
                        float* dst = &xpstage[cn & 1][0];
#pragma unroll
                        for (int q = 0; q < 24; ++q) {
                            float4 v = *(const float4*)&src[q * 256 + l * 4];
                            *(float4*)&dst[q * 256 + l * 4] = v;
                        }
                        if (l < CH) maskst[cn & 1][l] = mask[bTT + cn * CH + l];
                    }
                    const int cf = (i >> 5) - 2;              // flush pot chunk cf
                    if (cf >= 0) {
                        const float* srcl = &potring[(cf & 1) * 32][0];
                        float* dstg = potg + (size_t)cf * CH * KK;
#pragma unroll
                        for (int q = 0; q < 4; ++q) {
                            float4 v = *(const float4*)&srcl[q * 256 + l * 4];
                            *(float4*)&dstg[q * 256 + l * 4] = v;
                        }
                    }
                }
                // publish chunk flushed 4 steps ago (stores long complete ->
                // the fence drains nothing; vmcnt is wave-scalar so lane0's
                // waitcnt covers the whole wave's flush stores)
                if ((i & 31) == 4 && l == 0) {
                    const int cp = (i >> 5) - 2;
                    if (cp >= 0) {
                        __threadfence();
                        atomicExch(&g_pflags[b * 32 + cp], 1);
                    }
                }
                const int t = i - 2;
                if (t >= 0 && t < TT) {
                    const float4* hv4 = (const float4*)&hbuf[t & 3][0];
                    float p0 = dbk, p1 = 0.f, p2 = 0.f, p3 = 0.f;
#pragma unroll
                    for (int c = 0; c < 16; ++c) {
                        float4 hv = hv4[c];
                        p0 += hv.x * dk[4 * c + 0];
                        p1 += hv.y * dk[4 * c + 1];
                        p2 += hv.z * dk[4 * c + 2];
                        p3 += hv.w * dk[4 * c + 3];
                    }
                    float pot = (p0 + p1) + (p2 + p3);
                    if (t == 0) pot += lbk;
                    if (t == sl - 1) pot += rbk;
                    if (l < 32) potring[t & 63][k] = pot;
                }
                __syncthreads();
            }
            // flush last pot chunk (31), publish 30 and 31
            {
                const float* srcl = &potring[(31 & 1) * 32][0];
                float* dstg = potg + (size_t)31 * CH * KK;
#pragma unroll
                for (int q = 0; q < 4; ++q) {
                    float4 v = *(const float4*)&srcl[q * 256 + l * 4];
                    *(float4*)&dstg[q * 256 + l * 4] = v;
                }
                if (l == 0) {
                    __threadfence();
                    atomicExch(&g_pflags[b * 32 + 30], 1);
                    atomicExch(&g_pflags[b * 32 + 31], 1);
                }
            }
        }
        return;
    }

    // =================== VIT block (R8 verbatim) ============================
    const int b = blockIdx.x - BB;
    const int bTT = b * TT;
    const float* potg = out_pot + (size_t)bTT * KK;
    const int k = l & 31;
    const int hf = l >> 5;
    const int addrx = (l ^ 32) * 4;

    unsigned char* bp    = smem;                                   // 32736
    unsigned char* table = smem + 32736;                           // 32768
    float (*potbuf)[CH][KK] = (float (*)[CH][KK])(smem + 65504);   // 8192
    int* ent        = (int*)(smem + 73696);                        // 128
    int* last_tag_s = (int*)(smem + 73824);                        // 4

    float ccol[16];
    int addr[16];
    if (w == 1) {
#pragma unroll
        for (int m = 0; m < 16; ++m) {
            ccol[m] = chain[(hf * 16 + m) * KK + k];
            addr[m] = (hf * 16 + m) * 4;
        }
#pragma unroll
        for (int m = 0; m < 16; ++m) asm volatile("" : "+v"(ccol[m]));
    }
    // stage chunk 0
    if (w == 0) {
        if (l == 0) {
            while (atomicAdd(&g_pflags[b * 32 + 0], 0) == 0) __builtin_amdgcn_s_sleep(8);
        }
        __threadfence();                                  // acquire
#pragma unroll
        for (int q = 0; q < 4; ++q) {
            float4 v = *(const float4*)&potg[(size_t)(q * 64 + l) * 4];
            ((float4*)&potbuf[0][0][0])[q * 64 + l] = v;
        }
    }
    __syncthreads();                                      // B0: chunk 0 ready
    float s = 0.f;
    for (int c = 0; c < 32; ++c) {
        if (w == 0 && c + 1 < 32) {                       // stage chunk c+1
            if (l == 0) {
                while (atomicAdd(&g_pflags[b * 32 + c + 1], 0) == 0)
                    __builtin_amdgcn_s_sleep(8);
            }
            __threadfence();
            const float* src = potg + (size_t)(c + 1) * CH * KK;
#pragma unroll
            for (int q = 0; q < 4; ++q) {
                float4 v = *(const float4*)&src[(size_t)(q * 64 + l) * 4];
                ((float4*)&potbuf[(c + 1) & 1][0][0])[q * 64 + l] = v;
            }
        }
        if (w == 1) {                                     // viterbi chunk c
            for (int ll = 0; ll < 32; ++ll) {
                const int t = c * 32 + ll;
                float pot = potbuf[c & 1][ll][k];
                if (t == 0) {
                    s = pot;
                } else {
                    const int si = __float_as_int(s);
                    float cc[16];
#pragma unroll
                    for (int m = 0; m < 16; ++m)
                        cc[m] = __int_as_float(__builtin_amdgcn_ds_bpermute(addr[m], si)) + ccol[m];
                    float v1[8]; int i1[8];
#pragma unroll
                    for (int p = 0; p < 8; ++p) {
                        bool tk = cc[2 * p + 1] > cc[2 * p];
                        v1[p] = tk ? cc[2 * p + 1] : cc[2 * p];
                        i1[p] = hf * 16 + (tk ? 2 * p + 1 : 2 * p);
                    }
                    float v2[4]; int i2[4];
#pragma unroll
                    for (int p = 0; p < 4; ++p) {
                        bool tk = v1[2 * p + 1] > v1[2 * p];
                        v2[p] = tk ? v1[2 * p + 1] : v1[2 * p];
                        i2[p] = tk ? i1[2 * p + 1] : i1[2 * p];
                    }
                    float v3[2]; int i3[2];
#pragma unroll
                    for (int p = 0; p < 2; ++p) {
                        bool tk = v2[2 * p + 1] > v2[2 * p];
                        v3[p] = tk ? v2[2 * p + 1] : v2[2 * p];
                        i3[p] = tk ? i2[2 * p + 1] : i2[2 * p];
                    }
                    bool tk = v3[1] > v3[0];
                    float bv = tk ? v3[1] : v3[0];
                    int bi = tk ? i3[1] : i3[0];
                    float ov = __int_as_float(__builtin_amdgcn_ds_bpermute(addrx, __float_as_int(bv)));
                    int   oi = __builtin_amdgcn_ds_bpermute(addrx, bi);
                    bool take = (ov > bv) || (ov == bv && oi < bi);
                    if (take) { bv = ov; bi = oi; }
                    if (l < 32) bp[(t - 1) * KK + k] = (unsigned char)bi;
                    s = bv + pot;
                }
            }
        }
        __syncthreads();                                  // chunk boundary
    }
    if (w == 1) {                                         // last tag
        float bv = s; int bi = k;
#pragma unroll
        for (int d = 16; d >= 1; d >>= 1) {
            float ov = __shfl_xor(bv, d, 64);
            int   oi = __shfl_xor(bi, d, 64);
            bool take = (ov > bv) || (ov == bv && oi < bi);
            if (take) { bv = ov; bi = oi; }
        }
        if (l == 0) *last_tag_s = bi;
    }
    __syncthreads();
    // ---- Phase A: chunk-parallel backtrack (8 groups over 32 chunks) ----
    {
        const int kk2 = tid & 31;
        const int grp = tid >> 5;                         // 0..7
        for (int c = grp; c < 32; c += 8) {
            int tag = kk2;
            for (int ll = 31; ll >= 0; --ll) {
                const int t = c * 32 + ll;
                if (t < TT - 1) tag = bp[t * KK + tag];
                table[(c * 32 + ll) * KK + kk2] = (unsigned char)tag;
            }
        }
    }
    __syncthreads();
    if (tid == 0) {                                       // Phase B: stitch
        int e = *last_tag_s;
        ent[31] = e;
        for (int c = 30; c >= 0; --c) { e = table[(c + 1) * 32 * KK + e]; ent[c] = e; }
    }
    __syncthreads();
    for (int t = tid; t < TT; t += 256) {                 // Phase C: emit
        const int c = t >> 5, ll = t & 31;
        out_dec[(size_t)bTT + t] = (float)table[(c * 32 + ll) * KK + ent[c]];
    }
    if (blockIdx.x == BB) {
        for (int i2 = tid; i2 < KK * KK; i2 += 256) out_chn[i2] = chain[i2];
    }
    // re-zero this batch's flags for the next launch/replay
    for (int i2 = tid; i2 < 32; i2 += 256) atomicExch(&g_pflags[b * 32 + i2], 0);
}

// ---------------------------------------------------------------------------
extern "C" void kernel_launch(void* const* d_in, const int* in_sizes, int n_in,
                              void* d_out, int out_size, void* d_ws, size_t ws_size,
                              hipStream_t stream) {
    const float* X     = (const float*)d_in[0];
    const int*   mask  = (const int*)d_in[1];
    const float* Wk    = (const float*)d_in[2];   // [128,192]
    const float* Wr    = (const float*)d_in[3];   // [64,192]
    const float* gb    = (const float*)d_in[4];   // [2,192]
    const float* Dk    = (const float*)d_in[5];   // [64,32]
    const float* db    = (const float*)d_in[6];   // [32]
    const float* chain = (const float*)d_in[7];   // [32,32]
    const float* lb    = (const float*)d_in[8];
    const float* rb    = (const float*)d_in[9];

    float* out = (float*)d_out;
    float* out_dec  = out;                                   // [B,T]
    float* out_pot  = out + (size_t)BB * TT;                 // [B,T,K]
    float* out_slen = out + (size_t)BB * TT + (size_t)BB * TT * KK;        // [B]
    float* out_chn  = out_slen + BB;                         // [K,K]

    float* xp = (float*)d_ws;                                // [B*T,192]

    xproj_kernel<<<dim3((BB * TT) / 64, 3), dim3(256), 0, stream>>>(X, Wk, gb, xp);
    gruvit_kernel<<<dim3(2 * BB), dim3(256), 0, stream>>>(xp, Wr, gb, mask, Dk, db,
                                                          chain, lb, rb, out_pot,
                                                          out_dec, out_slen, out_chn);
}